// Round 5
// baseline (200.495 us; speedup 1.0000x reference)
//
#include <hip/hip_runtime.h>
#include <hip/hip_bf16.h>

#define BB   128
#define CIN  9
#define TT   2048
#define RR   512
#define NN   (BB*RR)     // 65536
#define HID  128
#define NOUT 12

typedef __attribute__((ext_vector_type(8))) short short8;
typedef __attribute__((ext_vector_type(4))) float f32x4;

static __device__ inline unsigned short f2bf(float f) {       // RNE f32->bf16
    unsigned int u = __float_as_uint(f);
    unsigned int r = (u + 0x7fffu + ((u >> 16) & 1u)) >> 16;
    return (unsigned short)r;
}
static __device__ inline float bf2f(unsigned short u) {
    return __uint_as_float(((unsigned int)u) << 16);
}

// =======================================================================
// k_convs: [unchanged from R4 — conv taps via wave-uniform s_load]
//   block 0       : tiny prep — zero meanbuf/done, W2^T bf16 transpose.
//   blocks 1..64  : dense-A build, 8 rows each, LDS-local.
//   blocks 65..1088: fused conv1+relu+pool2 -> conv2+relu+pool2 -> nodesT.
// =======================================================================
__global__ __launch_bounds__(512) void k_convs(const float* __restrict__ x,
        const float* __restrict__ w1, const float* __restrict__ b1,
        const float* __restrict__ w2, const float* __restrict__ b2,
        unsigned short* __restrict__ nodesT,
        const int* __restrict__ ei, int E, int es,
        unsigned short* __restrict__ Ab16,
        const float* __restrict__ g2w, unsigned short* __restrict__ w2t,
        float* __restrict__ meanbuf, int* __restrict__ done) {
    __shared__ __align__(16) union {
        struct { float sx[CIN][268]; float s1[16][132]; } c;   // conv: 18.1 KB
        struct { int cnt[512]; float arow[8][512]; } a;        // A-build: 18.4 KB
    } u;
    int tid = threadIdx.x;
    int bid = blockIdx.x;

    if (bid == 0) {                    // ---- tiny prep ----
        float4 z = make_float4(0.f, 0.f, 0.f, 0.f);
        for (int i = tid; i < 128 * 128 / 4; i += 512) ((float4*)meanbuf)[i] = z;
        if (tid < 128) done[tid] = 0;
        for (int idx = tid; idx < 128 * 128; idx += 512) {
            int c2 = idx >> 7, f = idx & 127;
            w2t[f * 128 + c2] = f2bf(g2w[idx]);
        }
        return;
    }

    if (bid <= 64) {                   // ---- dense-A build: rows [base, base+8) ----
        int base = (bid - 1) * 8;
        u.a.cnt[tid] = 0;
        float4 z = make_float4(0.f, 0.f, 0.f, 0.f);
        float4* az = (float4*)u.a.arow;      // 1024 float4
        az[tid] = z; az[tid + 512] = z;
        __syncthreads();
        for (int i = tid; i < es; i += 512) atomicAdd(&u.a.cnt[ei[E + i]], 1);
        __syncthreads();
        for (int i = tid; i < es; i += 512) {
            int c = ei[E + i];
            if (c >= base && c < base + 8) {
                int r = ei[i];
                float nd = rsqrtf((float)u.a.cnt[r] + 1.0f);
                float dn = rsqrtf((float)u.a.cnt[c] + 1.0f);
                atomicAdd(&u.a.arow[c - base][r], nd * dn);
            }
        }
        if (tid < 8) {                 // self loop
            int r = base + tid;
            float d = rsqrtf((float)u.a.cnt[r] + 1.0f);
            atomicAdd(&u.a.arow[tid][r], d * d);
        }
        __syncthreads();
        {   // convert 8x512 fp32 -> bf16, coalesced row stores
            int row = tid >> 6, c0 = (tid & 63) * 8;
            const float* p = &u.a.arow[row][c0];
            ushort4 o0, o1;
            o0.x = f2bf(p[0]); o0.y = f2bf(p[1]); o0.z = f2bf(p[2]); o0.w = f2bf(p[3]);
            o1.x = f2bf(p[4]); o1.y = f2bf(p[5]); o1.z = f2bf(p[6]); o1.w = f2bf(p[7]);
            *(ushort4*)&Ab16[(size_t)(base + row) * 512 + c0]     = o0;
            *(ushort4*)&Ab16[(size_t)(base + row) * 512 + c0 + 4] = o1;
        }
        return;
    }

    int cb = bid - 65;
    int b  = cb >> 3;
    int r0 = (cb & 7) * 64;
    int wv   = __builtin_amdgcn_readfirstlane(tid >> 6);   // wave 0..7
    int lane = tid & 63;

    for (int idx = tid; idx < CIN * 268; idx += 512) {
        int c = idx / 268, j = idx - c * 268;
        int g = 4 * r0 - 6 + j;
        float v = 0.f;
        if (g >= 0 && g < TT) v = x[(b * CIN + c) * TT + g];
        u.c.sx[c][j] = v;
    }
    __syncthreads();

    // phase B: wave wv covers channels wv*2, wv*2+1 (taps via s_load)
    {
        int c1a = wv * 2, c1b = wv * 2 + 1;
        float biasA = b1[c1a], biasB = b1[c1b];
        for (int pp = lane; pp < 132; pp += 64) {
            int p = 2 * r0 - 2 + pp;
            float valA = 0.f, valB = 0.f;
            if (p >= 0 && p < 1024) {
                float a0A = biasA, a1A = biasA, a0B = biasB, a1B = biasB;
#pragma unroll
                for (int c = 0; c < CIN; ++c) {
                    const float2* px = (const float2*)&u.c.sx[c][2 * pp];
                    float2 q0 = px[0], q1 = px[1], q2 = px[2];
                    {
                        const float* wp = &w1[(c1a * CIN + c) * 5];
                        float k0 = wp[0], k1 = wp[1], k2 = wp[2], k3 = wp[3], k4 = wp[4];
                        a0A += q0.x*k0 + q0.y*k1 + q1.x*k2 + q1.y*k3 + q2.x*k4;
                        a1A += q0.y*k0 + q1.x*k1 + q1.y*k2 + q2.x*k3 + q2.y*k4;
                    }
                    {
                        const float* wp = &w1[(c1b * CIN + c) * 5];
                        float k0 = wp[0], k1 = wp[1], k2 = wp[2], k3 = wp[3], k4 = wp[4];
                        a0B += q0.x*k0 + q0.y*k1 + q1.x*k2 + q1.y*k3 + q2.x*k4;
                        a1B += q0.y*k0 + q1.x*k1 + q1.y*k2 + q2.x*k3 + q2.y*k4;
                    }
                }
                valA = fmaxf(fmaxf(a0A, a1A), 0.f);
                valB = fmaxf(fmaxf(a0B, a1B), 0.f);
            }
            u.c.s1[c1a][pp] = valA;
            u.c.s1[c1b][pp] = valB;
        }
    }
    __syncthreads();

    // phase C: wave wv covers channels wv*4..wv*4+3 -> nodesT bf16
    int rl = lane;
    float acc0[4], acc1[4];
#pragma unroll
    for (int o = 0; o < 4; ++o) {
        float bv = b2[wv * 4 + o];
        acc0[o] = bv; acc1[o] = bv;
    }
#pragma unroll
    for (int c = 0; c < 16; ++c) {
        const float2* ps = (const float2*)&u.c.s1[c][2 * rl];
        float2 q0 = ps[0], q1 = ps[1], q2 = ps[2];
#pragma unroll
        for (int o = 0; o < 4; ++o) {
            const float* wp = &w2[((wv * 4 + o) * 16 + c) * 5];
            float k0 = wp[0], k1 = wp[1], k2 = wp[2], k3 = wp[3], k4 = wp[4];
            acc0[o] += q0.x*k0 + q0.y*k1 + q1.x*k2 + q1.y*k3 + q2.x*k4;
            acc1[o] += q0.y*k0 + q1.x*k1 + q1.y*k2 + q2.x*k3 + q2.y*k4;
        }
    }
    int n = r0 + rl;
    unsigned short* np = nodesT + ((size_t)b * 32 + wv * 4) * 512 + n;
    np[0]    = f2bf(fmaxf(fmaxf(acc0[0], acc1[0]), 0.f));
    np[512]  = f2bf(fmaxf(fmaxf(acc0[1], acc1[1]), 0.f));
    np[1024] = f2bf(fmaxf(fmaxf(acc0[2], acc1[2]), 0.f));
    np[1536] = f2bf(fmaxf(fmaxf(acc0[3], acc1[3]), 0.f));
}

// =======================================================================
// k_agg1: [unchanged from R4]
// =======================================================================
__global__ __launch_bounds__(256) void k_agg1(const unsigned short* __restrict__ Ab,
        const unsigned short* __restrict__ nT, const float* __restrict__ w1,
        const float* __restrict__ b1, unsigned short* __restrict__ h16) {
    __shared__ unsigned short sA[128][72];
    __shared__ unsigned short sN[32][72];
    __shared__ float sAgg[128][33];
    __shared__ float sw1[32 * 128];
    int tid = threadIdx.x;
    int b  = blockIdx.x >> 2;
    int rb = blockIdx.x & 3;
    int r0 = rb * 128;
    const unsigned short* nb = nT + (size_t)b * 32 * 512;

    {
        const float4* src = (const float4*)w1;
        float4* dst = (float4*)sw1;
#pragma unroll
        for (int i = 0; i < 4; ++i) dst[tid + i * 256] = src[tid + i * 256];
    }

    int wv = tid >> 6, lane = tid & 63;
    int l15 = lane & 15, quad = lane >> 4;
    int mB = wv * 32;
    f32x4 acc[2][2];
#pragma unroll
    for (int i = 0; i < 2; ++i)
#pragma unroll
        for (int j = 0; j < 2; ++j) acc[i][j] = (f32x4){0.f, 0.f, 0.f, 0.f};

    for (int kt = 0; kt < 8; ++kt) {
        int k0 = kt * 64;
        __syncthreads();
#pragma unroll
        for (int i = 0; i < 8; ++i) {
            int idx = tid + i * 256;
            int row = idx >> 4, c4 = (idx & 15) * 4;
            *(ushort4*)&sA[row][c4] = *(const ushort4*)&Ab[(size_t)(r0 + row) * 512 + k0 + c4];
        }
#pragma unroll
        for (int i = 0; i < 2; ++i) {
            int idx = tid + i * 256;
            int f = idx >> 4, c4 = (idx & 15) * 4;
            *(ushort4*)&sN[f][c4] = *(const ushort4*)&nb[(size_t)f * 512 + k0 + c4];
        }
        __syncthreads();
#pragma unroll
        for (int ks = 0; ks < 2; ++ks) {
            int kk = ks * 32 + quad * 8;
            short8 av0 = *(const short8*)&sA[mB + l15][kk];
            short8 av1 = *(const short8*)&sA[mB + 16 + l15][kk];
            short8 bv0 = *(const short8*)&sN[l15][kk];
            short8 bv1 = *(const short8*)&sN[16 + l15][kk];
            acc[0][0] = __builtin_amdgcn_mfma_f32_16x16x32_bf16(av0, bv0, acc[0][0], 0, 0, 0);
            acc[0][1] = __builtin_amdgcn_mfma_f32_16x16x32_bf16(av0, bv1, acc[0][1], 0, 0, 0);
            acc[1][0] = __builtin_amdgcn_mfma_f32_16x16x32_bf16(av1, bv0, acc[1][0], 0, 0, 0);
            acc[1][1] = __builtin_amdgcn_mfma_f32_16x16x32_bf16(av1, bv1, acc[1][1], 0, 0, 0);
        }
    }
    __syncthreads();
#pragma unroll
    for (int mi = 0; mi < 2; ++mi)
#pragma unroll
        for (int ni = 0; ni < 2; ++ni)
#pragma unroll
            for (int r = 0; r < 4; ++r)
                sAgg[mB + mi * 16 + quad * 4 + r][ni * 16 + l15] = acc[mi][ni][r];
    __syncthreads();

    int fq = tid & 31;
    int ng = tid >> 5;
    float4 bv = *(const float4*)&b1[fq * 4];
    for (int ch = 0; ch < 4; ++ch) {
        float a[4][4];
#pragma unroll
        for (int j = 0; j < 4; ++j)
#pragma unroll
            for (int q = 0; q < 4; ++q) a[j][q] = 0.f;
#pragma unroll
        for (int c = 0; c < 32; ++c) {
            float4 wvv = *(const float4*)&sw1[c * 128 + fq * 4];
#pragma unroll
            for (int j = 0; j < 4; ++j) {
                float xc = sAgg[ch * 32 + ng * 4 + j][c];
                a[j][0] += xc * wvv.x; a[j][1] += xc * wvv.y;
                a[j][2] += xc * wvv.z; a[j][3] += xc * wvv.w;
            }
        }
#pragma unroll
        for (int j = 0; j < 4; ++j) {
            ushort4 o;
            o.x = f2bf(fmaxf(a[j][0] + bv.x, 0.f));
            o.y = f2bf(fmaxf(a[j][1] + bv.y, 0.f));
            o.z = f2bf(fmaxf(a[j][2] + bv.z, 0.f));
            o.w = f2bf(fmaxf(a[j][3] + bv.w, 0.f));
            *(ushort4*)&h16[(size_t)(b * 512 + r0 + ch * 32 + ng * 4 + j) * 128 + fq * 4] = o;
        }
    }
}

// =======================================================================
// k_fused2: per-sample fused  lin2 + agg2 + mean + fc.
//   2 blocks/sample (M=256 rows of A_hat each), 512 threads, 160 KB LDS
//   -> exactly 1 block/CU, 256 blocks.
//   Phase 1: t^T[f][node] = (h1_b @ W2)^T into LDS (swapped-operand MFMA,
//            W2^T frags in registers, h1 chunks staged XOR-swizzled).
//   Phase 2: out = A_panel @ t, A staged reg->LDS XOR-swizzled, issue-early.
//   Epilogue: bias+relu+colsum -> meanbuf atomics -> last block fc.
// =======================================================================
__global__ __launch_bounds__(512) void k_fused2(
        const unsigned short* __restrict__ h1,    // [N][128] bf16
        const unsigned short* __restrict__ w2t,   // [128][128] bf16 (f-major)
        const unsigned short* __restrict__ Ab,    // [512][512] bf16
        const float* __restrict__ b2,
        float* __restrict__ meanbuf, int* __restrict__ done,
        const float* __restrict__ fw, const float* __restrict__ fb,
        float* __restrict__ out) {
    // one flat 160 KiB block: tLds = bytes [0, 131072), sA = [131072, 163840)
    __shared__ __align__(16) unsigned short smem[81920];
    char* tL = (char*)smem;            // t^T[f][node]: byte f*1024 + node*2, ^((f&7)<<4)
    char* sS = (char*)smem + 131072;   // 32 KB staging

    int tid  = threadIdx.x;
    int smp  = blockIdx.x >> 1;
    int r0   = (blockIdx.x & 1) * 256;
    int wv   = __builtin_amdgcn_readfirstlane(tid >> 6);
    int lane = tid & 63;
    int l15  = lane & 15, quad = lane >> 4;
    const unsigned short* hb = h1 + (size_t)smp * 512 * 128;

    // preload W2^T fragments for this wave's f-tile (rows wv*16..wv*16+15)
    short8 w2r[4];
#pragma unroll
    for (int ks = 0; ks < 4; ++ks)
        w2r[ks] = *(const short8*)&w2t[(wv * 16 + l15) * 128 + ks * 32 + quad * 8];

    uint4 stg[4];
    // ---------------- phase 1: t^T into LDS, 4 chunks of 128 nodes ------
#pragma unroll
    for (int i = 0; i < 4; ++i) {      // prefetch chunk 0 (h1: [128][128])
        int idx = tid + i * 512;
        stg[i] = *(const uint4*)&hb[(size_t)(idx >> 4) * 128 + (idx & 15) * 8];
    }
    for (int ch = 0; ch < 4; ++ch) {
#pragma unroll
        for (int i = 0; i < 4; ++i) {  // swizzled write: row stride 256 B, 16 slots
            int idx = tid + i * 512;
            int row = idx >> 4, c16 = idx & 15;
            *(uint4*)(sS + row * 256 + ((c16 ^ (row & 7)) << 4)) = stg[i];
        }
        __syncthreads();
        if (ch < 3) {                  // prefetch next chunk (overlaps MFMA)
#pragma unroll
            for (int i = 0; i < 4; ++i) {
                int idx = tid + i * 512;
                stg[i] = *(const uint4*)&hb[(size_t)((ch + 1) * 128 + (idx >> 4)) * 128 + (idx & 15) * 8];
            }
        }
        f32x4 acc1[8];
#pragma unroll
        for (int nf = 0; nf < 8; ++nf) acc1[nf] = (f32x4){0.f, 0.f, 0.f, 0.f};
#pragma unroll
        for (int ks = 0; ks < 4; ++ks) {
#pragma unroll
            for (int nf = 0; nf < 8; ++nf) {
                int row = nf * 16 + l15;
                short8 hf = *(const short8*)(sS + row * 256 + (((ks * 4 + quad) ^ (row & 7)) << 4));
                acc1[nf] = __builtin_amdgcn_mfma_f32_16x16x32_bf16(w2r[ks], hf, acc1[nf], 0, 0, 0);
            }
        }
        // write t^T[f][node] bf16 (conflict-free: consecutive lanes = consecutive node)
#pragma unroll
        for (int nf = 0; nf < 8; ++nf) {
#pragma unroll
            for (int r = 0; r < 4; ++r) {
                int f = wv * 16 + quad * 4 + r;
                int node = ch * 128 + nf * 16 + l15;
                *(unsigned short*)(tL + ((f * 1024 + node * 2) ^ ((f & 7) << 4))) = f2bf(acc1[nf][r]);
            }
        }
        __syncthreads();
    }

    // ---------------- phase 2: A_panel[256x512] @ t -> acc --------------
    int m_off = (wv >> 1) * 64;
    int f_off = (wv & 1) * 64;
    f32x4 acc[4][4];
#pragma unroll
    for (int i = 0; i < 4; ++i)
#pragma unroll
        for (int j = 0; j < 4; ++j) acc[i][j] = (f32x4){0.f, 0.f, 0.f, 0.f};

#pragma unroll
    for (int i = 0; i < 4; ++i) {      // prefetch A panel kt=0: [256][64]
        int idx = tid + i * 512;
        stg[i] = *(const uint4*)&Ab[(size_t)(r0 + (idx >> 3)) * 512 + (idx & 7) * 8];
    }
    for (int kt = 0; kt < 8; ++kt) {
#pragma unroll
        for (int i = 0; i < 4; ++i) {  // swizzled write: row stride 128 B, 8 slots
            int idx = tid + i * 512;
            int row = idx >> 3, c16 = idx & 7;
            *(uint4*)(sS + row * 128 + ((c16 ^ (row & 7)) << 4)) = stg[i];
        }
        __syncthreads();
        if (kt < 7) {                  // prefetch next panel (overlaps MFMA)
#pragma unroll
            for (int i = 0; i < 4; ++i) {
                int idx = tid + i * 512;
                stg[i] = *(const uint4*)&Ab[(size_t)(r0 + (idx >> 3)) * 512 + (kt + 1) * 64 + (idx & 7) * 8];
            }
        }
#pragma unroll
        for (int ks = 0; ks < 2; ++ks) {
            short8 af[4], bfr[4];
#pragma unroll
            for (int mi = 0; mi < 4; ++mi) {
                int row = m_off + mi * 16 + l15;
                af[mi] = *(const short8*)(sS + row * 128 + (((ks * 4 + quad) ^ (row & 7)) << 4));
            }
#pragma unroll
            for (int ni = 0; ni < 4; ++ni) {
                int f = f_off + ni * 16 + l15;
                int k = kt * 64 + ks * 32 + quad * 8;
                bfr[ni] = *(const short8*)(tL + ((f * 1024 + k * 2) ^ ((f & 7) << 4)));
            }
#pragma unroll
            for (int mi = 0; mi < 4; ++mi)
#pragma unroll
                for (int ni = 0; ni < 4; ++ni)
                    acc[mi][ni] = __builtin_amdgcn_mfma_f32_16x16x32_bf16(af[mi], bfr[ni], acc[mi][ni], 0, 0, 0);
        }
        __syncthreads();               // panel reads done before next overwrite
    }

    // ---------------- epilogue: bias+relu+colsum -> meanbuf -> fc -------
    float colsum[4];
#pragma unroll
    for (int ni = 0; ni < 4; ++ni) {
        int f = f_off + ni * 16 + l15;
        float bc = b2[f];
        float s = 0.f;
#pragma unroll
        for (int mi = 0; mi < 4; ++mi)
#pragma unroll
            for (int r = 0; r < 4; ++r)
                s += fmaxf(acc[mi][ni][r] + bc, 0.f);
        s += __shfl_xor(s, 16);        // combine quads (same f, different m)
        s += __shfl_xor(s, 32);
        colsum[ni] = s;                // 64-row sum, valid all lanes
    }
    float* sred = (float*)sS;          // reuse staging: [8 waves][64 f]
    float* smv  = sred + 512;
    int*  slastp = (int*)(smv + 128);
    if (lane < 16) {
#pragma unroll
        for (int ni = 0; ni < 4; ++ni) sred[wv * 64 + ni * 16 + lane] = colsum[ni];
    }
    __syncthreads();
    if (tid < 128) {
        int half = tid >> 6, fl = tid & 63;
        float s = sred[(half) * 64 + fl] + sred[(half + 2) * 64 + fl]
                + sred[(half + 4) * 64 + fl] + sred[(half + 6) * 64 + fl];
        atomicAdd(&meanbuf[smp * 128 + tid], s * (1.0f / RR));
    }
    __syncthreads();                   // meanbuf atomics drained (vmcnt 0)
    if (tid == 0) {
        __threadfence();               // release before flag
        *slastp = (atomicAdd(&done[smp], 1) == 1) ? 1 : 0;
    }
    __syncthreads();
    if (*slastp) {
        __threadfence();               // acquire
        if (tid < HID)
            smv[tid] = __hip_atomic_load(&meanbuf[smp * 128 + tid],
                                         __ATOMIC_RELAXED, __HIP_MEMORY_SCOPE_AGENT);
        __syncthreads();
        if (tid < NOUT) {
            float s = fb[tid];
#pragma unroll
            for (int c = 0; c < HID; ++c) s += smv[c] * fw[c * NOUT + tid];
            out[smp * NOUT + tid] = s;
        }
    }
}

extern "C" void kernel_launch(void* const* d_in, const int* in_sizes, int n_in,
                              void* d_out, int out_size, void* d_ws, size_t ws_size,
                              hipStream_t stream) {
    const float* x   = (const float*)d_in[0];
    const int*   ei  = (const int*)d_in[1];
    const float* c1w = (const float*)d_in[2];
    const float* c1b = (const float*)d_in[3];
    const float* c2w = (const float*)d_in[4];
    const float* c2b = (const float*)d_in[5];
    const float* g1w = (const float*)d_in[6];
    const float* g1b = (const float*)d_in[7];
    const float* g2w = (const float*)d_in[8];
    const float* g2b = (const float*)d_in[9];
    const float* fw  = (const float*)d_in[10];
    const float* fb  = (const float*)d_in[11];
    float* out = (float*)d_out;
    int E  = in_sizes[1] / 2;   // total edges (1048576)
    int es = E / BB;            // edges per sample graph (8192)

    char* ws = (char*)d_ws;
    unsigned short* nodesT = (unsigned short*)(ws);                 // 4 MB  [128][32][512] bf16
    unsigned short* h1     = (unsigned short*)(ws + (4u << 20));    // 16 MB [N][128] bf16
    unsigned short* Ab16   = (unsigned short*)(ws + (37u << 20));   // 512 KB dense A bf16
    float* meanbuf         = (float*)(ws + (37u << 20) + (512u << 10)); // 64 KB [128][128]
    int*   done            = (int*)  (ws + (37u << 20) + (576u << 10)); // 512 B [128]
    unsigned short* w2t    = (unsigned short*)(ws + (37u << 20) + (772u << 10)); // 32 KB

    // prep (block 0) + dense-A build (blocks 1..64) + convs (blocks 65..1088)
    k_convs<<<1089, 512, 0, stream>>>(x, c1w, c1b, c2w, c2b, nodesT,
                                      ei, E, es, Ab16, g2w, w2t, meanbuf, done);

    // GCN layer 1: dense MFMA aggregation + fp32 linear + relu -> h1 bf16
    k_agg1<<<512, 256, 0, stream>>>(Ab16, nodesT, g1w, g1b, h1);

    // GCN layer 2 fused: lin2 (t^T in LDS) + aggregation + mean + fc
    k_fused2<<<BB * 2, 512, 0, stream>>>(h1, w2t, Ab16, g2b,
                                         meanbuf, done, fw, fb, out);
}